// Round 10
// baseline (303.652 us; speedup 1.0000x reference)
//
#include <hip/hip_runtime.h>
#include <hip/hip_bf16.h>
#include <hip/hip_cooperative_groups.h>
#include <stdint.h>

namespace cg = cooperative_groups;

// ---------------------------------------------------------------------------
// EquivariantAttention on MI355X.  Dtype-adaptive (bf16 or fp32 inputs).
// R17: pre-converted bf16 q/k tiles + prebuilt W fragment images.  kB 58.6.
// R18: kAgg as per-(r-tile, head) MFMA GEMM.  tot 198.6.
// R19: kB ea@W1a -> MFMA (in-wave shfl A-frags).  kB 48.6, tot 188.8.
// R20: fused cooperative kernel attempt -> container failed twice (cause
//   ambiguous: infra flake vs coop-under-capture invalidation vs residency
//   deadlock at assumed 4 blocks/CU).
// R21: coop retry with failure modes closed:
//   (1) residency QUERIED via hipOccupancyMaxActiveBlocksPerMultiprocessor
//       (capture-safe host call) x CU count -> coop grid; launch only if
//       >=256 blocks fit (no deadlock from over-subscription).
//   (2) phases are grid-stride loops + inter-iteration barriers -> correct
//       at ANY grid size.
//   (3) one-shot: a failed coop launch disables coop for the process.
//   Fallback = R19-proven 4-dispatch pipeline (kA split 2 blocks/node).
// ---------------------------------------------------------------------------

#define NNODES 512
#define NDIM   480

// ws layout (4-byte word offsets)
#define QG_OFF    0u         // q bf16 tiles: [rt(32)][h(8)][row(16)][32 u32] = 131072 u32
#define W2B_OFF   131072u    // W2 B-frag bf16 per-lane image: 2048 u32
#define W3B_OFF   133120u    // W3 B-frag bf16 per-lane image: 512 u32
#define W1B_OFF   133632u    // W1a B-frag bf16 per-lane image: 1024 u32
#define KG_OFF    245760u    // k bf16 tiles, same layout as qG
#define VT_OFF    491520u    // v bf16 transposed: [h(8)][j(64)][s(512)] u16 = 512KB
#define ARE_OFF   737280u    // 512*288 u32 (bf16 pairs over o): [n][mi(9)][oc(32)]
#define ASN_OFF   884736u    // 512*288 u32
#define WF_OFF    1032192u   // W1a[32][64]@0, b1@6656, b2@6720, b3@6784
#define FLAG_OFF  1040384u   // flag[0] = 1 if inputs fp32, 0 if bf16 (fallback path)
#define L_OFF     1040448u   // L SoA: [h(8)][r(512)][s(512)] f32 (8MB)
#define WTQ_OFF   3137600u   // q weights transposed [o][i] f32 + folds
#define WTK_OFF   3159104u
#define WTV_OFF   3180608u
#define W1T_OFF   3202112u   // mW1 transposed [o(64)][row(480)] f32, cg folded

typedef float f32x4 __attribute__((ext_vector_type(4)));
typedef short s16x8 __attribute__((ext_vector_type(8)));

__device__ __forceinline__ float bf2f(uint16_t u) {
    return __uint_as_float(((uint32_t)u) << 16);
}
__device__ __forceinline__ uint16_t f2bf(float f) {
    union { __hip_bfloat16 h; uint16_t u; } cv;
    cv.h = __float2bfloat16(f);
    return cv.u;
}
__device__ __forceinline__ uint32_t packbf(float lo, float hi) {
    return ((uint32_t)f2bf(hi) << 16) | (uint32_t)f2bf(lo);
}
__device__ __forceinline__ float ldin(const void* p, size_t i, int f32) {
    return f32 ? ((const float*)p)[i] : bf2f(((const uint16_t*)p)[i]);
}
// tanh(x) = 1 - 2/(exp(2x)+1)
__device__ __forceinline__ float ftanh(float x) {
    float e = __builtin_amdgcn_exp2f(x * 2.885390081777927f);
    return 1.0f - 2.0f * __builtin_amdgcn_rcpf(e + 1.0f);
}

// =========================================================== phase W (weights)
__device__ void dPhaseW(
    const void* mW1, const void* mb1, const void* mW2, const void* mb2,
    const void* mW3, const void* mb3,
    const void* Wq0, const void* Wq1, const void* Wq2,
    const void* Wk0, const void* Wk1, const void* Wk2,
    const void* Wv0, const void* Wv1, const void* Wv2,
    float* ws, int f32, int gt, int gs)
{
    float* Wf = ws + WF_OFF;

    for (int i = gt; i < 2048; i += gs) Wf[i] = ldin(mW1, i, f32);   // W1a
    for (int i = gt; i < 64; i += gs) Wf[6656 + i] = ldin(mb1, i, f32);
    for (int i = gt; i < 64; i += gs) Wf[6720 + i] = ldin(mb2, i, f32);
    for (int i = gt; i < 8; i += gs)  Wf[6784 + i] = ldin(mb3, i, f32);

    {
        uint32_t* W2B = (uint32_t*)(ws + W2B_OFF);
        for (int i = gt; i < 2048; i += gs) {
            int f = i >> 8, lane = (i >> 2) & 63, w = i & 3;
            int nt = f >> 1, ks = f & 1, nl2 = lane & 15, gg = lane >> 4;
            int n = nt * 16 + nl2, kb = ks * 32 + gg * 8 + 2 * w;
            float lo = ldin(mW2, (size_t)kb * 64 + n, f32);
            float hi = ldin(mW2, (size_t)(kb + 1) * 64 + n, f32);
            W2B[i] = packbf(lo, hi);
        }
        uint32_t* W3B = (uint32_t*)(ws + W3B_OFF);
        for (int i = gt; i < 512; i += gs) {
            int ks = i >> 8, lane = (i >> 2) & 63, w = i & 3;
            int nl2 = lane & 15, gg = lane >> 4;
            int kb = ks * 32 + gg * 8 + 2 * w;
            float lo = (nl2 < 8) ? ldin(mW3, (size_t)kb * 8 + nl2, f32) : 0.f;
            float hi = (nl2 < 8) ? ldin(mW3, (size_t)(kb + 1) * 8 + nl2, f32) : 0.f;
            W3B[i] = packbf(lo, hi);
        }
        uint32_t* W1B = (uint32_t*)(ws + W1B_OFF);
        for (int i = gt; i < 1024; i += gs) {
            int nt = i >> 8, lane = (i >> 2) & 63, w = i & 3;
            int nl2 = lane & 15, gg = lane >> 4;
            int n = nt * 16 + nl2, k0 = gg * 8 + 2 * w;
            W1B[i] = packbf(ldin(mW1, (size_t)k0 * 64 + n, f32),
                            ldin(mW1, (size_t)(k0 + 1) * 64 + n, f32));
        }
    }

    const float e3n0 = 0.08838834764831845f, e3n1 = 0.125f, e3n2 = 0.17677669529663687f;
    const float cg1 = 0.5773502691896258f, cg2 = 0.4472135954999579f;
    const float attn = 0.1889822365046136f;

    const void* Wsrc[9] = {Wq0, Wq1, Wq2, Wk0, Wk1, Wk2, Wv0, Wv1, Wv2};
    float* Wdst[3] = {ws + WTQ_OFF, ws + WTK_OFF, ws + WTV_OFF};
    for (int kind = 0; kind < 3; ++kind) {
        const float f0 = (kind == 0) ? e3n0 * attn : e3n0;
        const float f1 = (kind == 0) ? e3n1 * cg1 * attn : e3n1;
        const float f2 = (kind == 0) ? e3n2 * cg2 * attn : e3n2;
        for (int i = gt; i < 16384; i += gs) {
            int o = i >> 7, ii = i & 127;
            Wdst[kind][i] = ldin(Wsrc[kind * 3], (size_t)ii * 128 + o, f32) * f0;
        }
        for (int i = gt; i < 4096; i += gs) {
            int o = i >> 6, ii = i & 63;
            Wdst[kind][16384 + i] = ldin(Wsrc[kind * 3 + 1], (size_t)ii * 64 + o, f32) * f1;
        }
        for (int i = gt; i < 1024; i += gs) {
            int o = i >> 5, ii = i & 31;
            Wdst[kind][20480 + i] = ldin(Wsrc[kind * 3 + 2], (size_t)ii * 32 + o, f32) * f2;
        }
    }
    float* W1T = ws + W1T_OFF;
    for (int i = gt; i < 30720; i += gs) {
        int o = i / 480, row = i - o * 480;
        float cgv;
        if (row < 160)      cgv = 1.0f;
        else if (row < 224) cgv = cg1;
        else if (row < 256) cgv = cg2;
        else if (row < 384) cgv = 1.0f;
        else if (row < 448) cgv = cg1;
        else                cgv = cg2;
        W1T[i] = ldin(mW1, (size_t)row * 64 + o, f32) * cgv;
    }
}

// ======================================================= phase A (per-node, half)
__device__ void dPhaseA(
    const void* nfu,
    const float* WtQ, const float* WtK, const float* WtV, const float* W1T,
    uint32_t* qG, uint32_t* kG, uint16_t* vT,
    uint32_t* ArecG, uint32_t* AsndG,
    int f32, int n, int half, float* nfs)
{
    const int t = threadIdx.x;
    for (int i = t; i < 480; i += 256) nfs[i] = ldin(nfu, (size_t)n * 480 + i, f32);

    // zero-fill tile pad (j = 60..63): half0 -> q,k (64 tasks); half1 -> v (32)
    if (half == 0) {
        if (t < 64) {
            const int kind2 = t >> 5, hh = (t >> 2) & 7, j = 60 + (t & 3);
            const int row = n & 15, rt = n >> 4;
            const int cc = (j >> 3) ^ (n & 7);
            uint16_t* dst = (uint16_t*)(kind2 == 0 ? qG : kG);
            dst[((((size_t)rt * 8 + hh) * 16 + row) * 8 + cc) * 8 + (j & 7)] = 0;
        }
    } else {
        if (t < 32) {
            const int hh = t >> 2, j = 60 + (t & 3);
            vT[((size_t)(hh * 64 + j)) * 512 + n] = 0;
        }
    }
    __syncthreads();

    for (int idx = 720 * half + t; idx < 720 * (half + 1); idx += 256) {
        int kind = idx / 480, rem = idx - kind * 480;
        int o, m, mul, d, off, am, qoff, sub;
        if (rem < 128)      { o = rem;           m = 0;          mul = 128; d = 1; off = 0;   am = 16; qoff = 0;  sub = 0; }
        else if (rem < 320) { int x = rem - 128; o = x / 3; m = x - o * 3; mul = 64;  d = 3; off = 128; am = 8;  qoff = 16; sub = 16384; }
        else                { int x = rem - 320; o = x / 5; m = x - o * 5; mul = 32;  d = 5; off = 320; am = 4;  qoff = 40; sub = 20480; }
        const float* base = (kind == 0) ? WtQ : (kind == 1) ? WtK : WtV;
        const float4* W4 = reinterpret_cast<const float4*>(base + sub + o * mul);
        const float* nf0 = nfs + off + m;
        float ax = 0.f, ay = 0.f, az = 0.f, aw = 0.f;
        const int n4 = mul >> 2;
        for (int i4 = 0; i4 < n4; ++i4) {
            float4 w = W4[i4];
            int ib = 4 * i4 * d;
            ax += nf0[ib]         * w.x;
            ay += nf0[ib + d]     * w.y;
            az += nf0[ib + 2 * d] * w.z;
            aw += nf0[ib + 3 * d] * w.w;
        }
        float acc = (ax + ay) + (az + aw);
        int hh = o / am, a = o - hh * am;
        int j = qoff + a * d + m;
        if (kind == 2) {
            vT[((size_t)(hh * 64 + j)) * 512 + n] = f2bf(acc);
        } else {
            const int row = n & 15, rt = n >> 4;
            const int cc = (j >> 3) ^ (n & 7);
            uint16_t* dst = (uint16_t*)(kind == 0 ? qG : kG);
            dst[((((size_t)rt * 8 + hh) * 16 + row) * 8 + cc) * 8 + (j & 7)] = f2bf(acc);
        }
    }

    // A-features: this half does src = half (o = lane of wave 0)
    if (t < 64) {
        const int src = half, o = t;
        float a[9];
        #pragma unroll
        for (int mi = 0; mi < 9; ++mi) {
            const int l = (mi == 0) ? 0 : (mi < 4 ? 1 : 2);
            const int m = (mi == 0) ? 0 : (mi < 4 ? mi - 1 : mi - 4);
            const int mul = (l == 0 ? 128 : l == 1 ? 64 : 32);
            const int d = 2 * l + 1;
            const int off = (l == 0 ? 0 : l == 1 ? 128 : 320);
            const int base = (src == 0) ? (l == 0 ? 32 : l == 1 ? 160 : 224)
                                        : (l == 0 ? 256 : l == 1 ? 384 : 448);
            const float4* W4 = reinterpret_cast<const float4*>(W1T + o * 480 + base);
            const float* nf0 = nfs + off + m;
            float ax = 0.f, ay = 0.f, az = 0.f, aw = 0.f;
            const int n4 = mul >> 2;
            for (int i4 = 0; i4 < n4; ++i4) {
                float4 w = W4[i4];
                int ib = 4 * i4 * d;
                ax += nf0[ib]         * w.x;
                ay += nf0[ib + d]     * w.y;
                az += nf0[ib + 2 * d] * w.z;
                aw += nf0[ib + 3 * d] * w.w;
            }
            a[mi] = (ax + ay) + (az + aw);
        }
        float b[9];
        #pragma unroll
        for (int mi = 0; mi < 9; ++mi) b[mi] = __shfl_xor(a[mi], 1, 64);
        if ((o & 1) == 0) {
            uint32_t* dst = (src ? AsndG : ArecG) + (size_t)n * 288 + (o >> 1);
            #pragma unroll
            for (int mi = 0; mi < 9; ++mi)
                dst[mi * 32] = ((uint32_t)f2bf(b[mi]) << 16) | (uint32_t)f2bf(a[mi]);
        }
    }
}

// ============================================== phase B (edge MLP + logits tile)
__device__ void dPhaseB(
    const void* eaG, const void* shG,
    const uint32_t* ArecG, const uint32_t* AsndG,
    const uint32_t* qG, const uint32_t* kG,
    const uint32_t* W2B, const uint32_t* W3B, const uint32_t* W1B,
    const float* Wf, float* L, int f32, int sx, int sy, uint32_t* smem)
{
    uint32_t* ArecS = smem;
    uint32_t* AsndS = smem + 4672;
    float* ewS = (float*)(smem + 8192);
    const int t = threadIdx.x;
    const int s0 = sx * 16, r0 = sy * 16;
    const int lane = t & 63, wv = t >> 6;
    const int g = lane >> 4, nl = lane & 15;

    const int rl = t >> 4, sl = t & 15;
    const int r = r0 + rl, s = s0 + sl;
    const size_t eidx = (((size_t)r) << 9) + s;

    uint32_t eaR[16];
    if (f32) {
        const float4* ep = reinterpret_cast<const float4*>((const float*)eaG + eidx * 32);
        #pragma unroll
        for (int i = 0; i < 8; ++i) {
            float4 v = ep[i];
            eaR[2 * i]     = ((uint32_t)f2bf(v.y) << 16) | (uint32_t)f2bf(v.x);
            eaR[2 * i + 1] = ((uint32_t)f2bf(v.w) << 16) | (uint32_t)f2bf(v.z);
        }
    } else {
        const uint4* ep = reinterpret_cast<const uint4*>((const uint32_t*)eaG + eidx * 16);
        #pragma unroll
        for (int i = 0; i < 4; ++i) {
            uint4 v = ep[i];
            eaR[4 * i] = v.x; eaR[4 * i + 1] = v.y; eaR[4 * i + 2] = v.z; eaR[4 * i + 3] = v.w;
        }
    }

    float sh0, sh1, sh2, sh3, sh4, sh5, sh6, sh7, sh8;
    {
        const size_t sb = eidx * 9;
        if (f32) {
            const float* shp = (const float*)shG + sb;
            sh0 = shp[0]; sh1 = shp[1]; sh2 = shp[2]; sh3 = shp[3]; sh4 = shp[4];
            sh5 = shp[5]; sh6 = shp[6]; sh7 = shp[7]; sh8 = shp[8];
        } else {
            const uint16_t* shp = (const uint16_t*)shG + sb;
            sh0 = bf2f(shp[0]); sh1 = bf2f(shp[1]); sh2 = bf2f(shp[2]);
            sh3 = bf2f(shp[3]); sh4 = bf2f(shp[4]); sh5 = bf2f(shp[5]);
            sh6 = bf2f(shp[6]); sh7 = bf2f(shp[7]); sh8 = bf2f(shp[8]);
        }
    }

    // ---- phase 1a: eaPart = ea @ W1a via MFMA ----
    {
        s16x8 w1f[4];
        #pragma unroll
        for (int nt = 0; nt < 4; ++nt) w1f[nt] = ((const s16x8*)W1B)[nt * 64 + lane];
        uint16_t* sm16 = (uint16_t*)smem;
        #pragma unroll
        for (int mm = 0; mm < 4; ++mm) {
            const int srcl = mm * 16 + nl;
            uint32_t af0 = 0, af1 = 0, af2 = 0, af3 = 0;
            #pragma unroll
            for (int c = 0; c < 16; ++c) {
                const uint32_t tmp = (uint32_t)__shfl((int)eaR[c], srcl, 64);
                if ((c >> 2) == g) {
                    if ((c & 3) == 0)      af0 = tmp;
                    else if ((c & 3) == 1) af1 = tmp;
                    else if ((c & 3) == 2) af2 = tmp;
                    else                   af3 = tmp;
                }
            }
            union { uint32_t u[4]; s16x8 v; } afc;
            afc.u[0] = af0; afc.u[1] = af1; afc.u[2] = af2; afc.u[3] = af3;
            const s16x8 afrag = afc.v;
            const int mt = wv * 4 + mm;
            #pragma unroll
            for (int nt = 0; nt < 4; ++nt) {
                f32x4 a = {0.f, 0.f, 0.f, 0.f};
                a = __builtin_amdgcn_mfma_f32_16x16x32_bf16(afrag, w1f[nt], a, 0, 0, 0);
                #pragma unroll
                for (int rg = 0; rg < 4; ++rg) {
                    const int e = mt * 16 + g * 4 + rg;
                    const int o = nt * 16 + nl;
                    sm16[e * 64 + (((o >> 3) ^ (e & 7)) << 3) + (o & 7)] = f2bf(a[rg]);
                }
            }
        }
    }

    // ---- h init: own row's ea-partial (intra-wave LDS dep) + b1 ----
    float h[64];
    #pragma unroll
    for (int c = 0; c < 8; ++c) {
        const int cc = c ^ (t & 7);
        const uint4 p = *(const uint4*)&smem[t * 32 + cc * 4];
        h[c * 8 + 0] = __uint_as_float(p.x << 16);
        h[c * 8 + 1] = __uint_as_float(p.x & 0xffff0000u);
        h[c * 8 + 2] = __uint_as_float(p.y << 16);
        h[c * 8 + 3] = __uint_as_float(p.y & 0xffff0000u);
        h[c * 8 + 4] = __uint_as_float(p.z << 16);
        h[c * 8 + 5] = __uint_as_float(p.z & 0xffff0000u);
        h[c * 8 + 6] = __uint_as_float(p.w << 16);
        h[c * 8 + 7] = __uint_as_float(p.w & 0xffff0000u);
    }
    #pragma unroll
    for (int o = 0; o < 64; ++o) h[o] += Wf[6656 + o];   // b1

    __syncthreads();   // all waves done reading ea-partial before restage

    for (int i = t; i < 16 * 288; i += 256) {
        int row = i / 288, c = i - row * 288;
        ArecS[row * 292 + c] = ArecG[(size_t)(r0 + row) * 288 + c];
        AsndS[row * 292 + c] = AsndG[(size_t)(s0 + row) * 288 + c];
    }
    __syncthreads();

    // ---- phase 1b: sh.(Arec+Asnd) ----
    {
        const int rb = rl * 292, sb = sl * 292;
        #pragma unroll 1
        for (int mi = 0; mi < 9; ++mi) {
            float shv = sh0;
            shv = (mi == 1) ? sh1 : shv;  shv = (mi == 2) ? sh2 : shv;
            shv = (mi == 3) ? sh3 : shv;  shv = (mi == 4) ? sh4 : shv;
            shv = (mi == 5) ? sh5 : shv;  shv = (mi == 6) ? sh6 : shv;
            shv = (mi == 7) ? sh7 : shv;  shv = (mi == 8) ? sh8 : shv;
            const int ro = rb + mi * 32, so = sb + mi * 32;
            #pragma unroll
            for (int oc = 0; oc < 32; ++oc) {
                uint32_t pa = ArecS[ro + oc];
                uint32_t pb = AsndS[so + oc];
                float a0 = __uint_as_float(pa << 16);
                float b0 = __uint_as_float(pb << 16);
                float a1 = __uint_as_float(pa & 0xffff0000u);
                float b1 = __uint_as_float(pb & 0xffff0000u);
                h[2 * oc]     += shv * (a0 + b0);
                h[2 * oc + 1] += shv * (a1 + b1);
            }
        }
    }

    #pragma unroll
    for (int o = 0; o < 64; ++o) h[o] = ftanh(h[o]);

    __syncthreads();   // all ArecS/AsndS reads complete before overwrite
    #pragma unroll
    for (int c = 0; c < 8; ++c) {
        const int cc = c ^ (t & 7);
        *(uint4*)&smem[t * 32 + cc * 4] =
            make_uint4(packbf(h[c * 8 + 0], h[c * 8 + 1]),
                       packbf(h[c * 8 + 2], h[c * 8 + 3]),
                       packbf(h[c * 8 + 4], h[c * 8 + 5]),
                       packbf(h[c * 8 + 6], h[c * 8 + 7]));
    }
    __builtin_amdgcn_sched_barrier(0);

    // ---- W2/W3 B-fragments: direct 16B loads of prebuilt per-lane images ----
    s16x8 w2f[4][2];
    #pragma unroll
    for (int nt = 0; nt < 4; ++nt) {
        #pragma unroll
        for (int ks = 0; ks < 2; ++ks)
            w2f[nt][ks] = ((const s16x8*)W2B)[(nt * 2 + ks) * 64 + lane];
    }
    s16x8 w3f[2];
    w3f[0] = ((const s16x8*)W3B)[lane];
    w3f[1] = ((const s16x8*)W3B)[64 + lane];
    float b2v[4];
    #pragma unroll
    for (int nt = 0; nt < 4; ++nt) b2v[nt] = Wf[6720 + nt * 16 + nl];
    const float b3v = (nl < 8) ? Wf[6784 + nl] : 0.f;

    // ---- phase 2 fused per-mm: layer2 -> tanh -> h2 pack -> layer3 -> ewS ----
    uint16_t* sm16 = (uint16_t*)smem;
    #pragma unroll 1
    for (int mm = 0; mm < 4; ++mm) {
        const int mt = wv * 4 + mm;
        const int row = mt * 16 + nl;
        const int sw0 = ((g    ) ^ (row & 7)) * 4;
        const int sw1 = ((4 + g) ^ (row & 7)) * 4;
        const s16x8 a0 = *(const s16x8*)&smem[row * 32 + sw0];
        const s16x8 a1 = *(const s16x8*)&smem[row * 32 + sw1];
        f32x4 acc[4];
        #pragma unroll
        for (int nt = 0; nt < 4; ++nt) {
            f32x4 a = {b2v[nt], b2v[nt], b2v[nt], b2v[nt]};
            a = __builtin_amdgcn_mfma_f32_16x16x32_bf16(a0, w2f[nt][0], a, 0, 0, 0);
            a = __builtin_amdgcn_mfma_f32_16x16x32_bf16(a1, w2f[nt][1], a, 0, 0, 0);
            acc[nt] = a;
        }
        const int e2base = mt * 16 + g * 4;
        #pragma unroll
        for (int nt = 0; nt < 4; ++nt) {
            const int n = nt * 16 + nl;
            #pragma unroll
            for (int rg = 0; rg < 4; ++rg) {
                const int e2 = e2base + rg;
                const int cc = (n >> 3) ^ (e2 & 7);
                sm16[e2 * 64 + cc * 8 + (n & 7)] = f2bf(ftanh(acc[nt][rg]));
            }
        }
        const s16x8 c0 = *(const s16x8*)&smem[row * 32 + sw0];
        const s16x8 c1 = *(const s16x8*)&smem[row * 32 + sw1];
        f32x4 a3 = {b3v, b3v, b3v, b3v};
        a3 = __builtin_amdgcn_mfma_f32_16x16x32_bf16(c0, w3f[0], a3, 0, 0, 0);
        a3 = __builtin_amdgcn_mfma_f32_16x16x32_bf16(c1, w3f[1], a3, 0, 0, 0);
        if (nl < 8) {
            #pragma unroll
            for (int rg = 0; rg < 4; ++rg) {
                const int e2 = mt * 16 + g * 4 + rg;
                ewS[nl * 256 + (e2 ^ (nl << 2))] = a3[rg];
            }
        }
    }

    __syncthreads();   // phase-2 h-tile reads + ewS writes complete

    // ---- phase 0a: copy prebuilt q/k bf16 tiles -> LDS (pure uint4 copy) ----
    {
        const uint4* qg4 = (const uint4*)qG + (size_t)sy * 1024;
        const uint4* kg4 = (const uint4*)kG + (size_t)sx * 1024;
        uint4* sm4 = (uint4*)smem;
        for (int i = t; i < 2048; i += 256)
            sm4[i] = (i < 1024) ? qg4[i] : kg4[i - 1024];
    }
    __syncthreads();

    // ---- phase 0b: logits = q.k via MFMA; L = logits + ew (single write) ----
    {
        const int sw0 = ((g    ) ^ (nl & 7)) << 2;
        const int sw1 = ((4 + g) ^ (nl & 7)) << 2;
        #pragma unroll
        for (int hh2 = 0; hh2 < 2; ++hh2) {
            const int h2 = wv * 2 + hh2;
            const uint32_t* qb = smem + h2 * 512;
            const uint32_t* kb = smem + 4096 + h2 * 512;
            const s16x8 qa0 = *(const s16x8*)&qb[nl * 32 + sw0];
            const s16x8 qa1 = *(const s16x8*)&qb[nl * 32 + sw1];
            const s16x8 ka0 = *(const s16x8*)&kb[nl * 32 + sw0];
            const s16x8 ka1 = *(const s16x8*)&kb[nl * 32 + sw1];
            f32x4 a = {0.f, 0.f, 0.f, 0.f};
            a = __builtin_amdgcn_mfma_f32_16x16x32_bf16(qa0, ka0, a, 0, 0, 0);
            a = __builtin_amdgcn_mfma_f32_16x16x32_bf16(qa1, ka1, a, 0, 0, 0);
            float* Lp = L + (((size_t)h2) << 18) + (((size_t)(r0 + g * 4)) << 9) + s0 + nl;
            #pragma unroll
            for (int rg = 0; rg < 4; ++rg) {
                const int e2 = (g * 4 + rg) * 16 + nl;
                Lp[(size_t)rg << 9] = a[rg] + ewS[h2 * 256 + (e2 ^ (h2 << 2))];
            }
        }
    }
}

// =============================================== phase Agg (softmax + PV GEMM)
__device__ void dPhaseAgg(
    const float* L, const uint16_t* vT,
    const void* nfu, void* out, int f32, int bx, int h, uint32_t* Ws)
{
    const int t = threadIdx.x;
    const int lane = t & 63, wv = t >> 6;
    const int g = lane >> 4, nl = lane & 15;
    const int r0 = bx * 16;

    {
        const int row = wv * 4 + g;
        const float* Lg = L + (((size_t)h) << 18) + (((size_t)(r0 + row)) << 9);
        float v[32];
        #pragma unroll
        for (int cw = 0; cw < 4; ++cw) {
            const float4* p = reinterpret_cast<const float4*>(Lg + nl * 8 + cw * 128);
            float4 x = p[0], y = p[1];
            v[cw * 8 + 0] = x.x; v[cw * 8 + 1] = x.y; v[cw * 8 + 2] = x.z; v[cw * 8 + 3] = x.w;
            v[cw * 8 + 4] = y.x; v[cw * 8 + 5] = y.y; v[cw * 8 + 6] = y.z; v[cw * 8 + 7] = y.w;
        }
        float mx = -3.402823466e38f;
        #pragma unroll
        for (int i = 0; i < 32; ++i) mx = fmaxf(mx, v[i]);
        #pragma unroll
        for (int off = 8; off >= 1; off >>= 1) mx = fmaxf(mx, __shfl_xor(mx, off, 16));
        const float C = 1.4426950408889634f;
        float sm = 0.f;
        #pragma unroll
        for (int i = 0; i < 32; ++i) {
            v[i] = __builtin_amdgcn_exp2f((v[i] - mx) * C);
            sm += v[i];
        }
        #pragma unroll
        for (int off = 8; off >= 1; off >>= 1) sm += __shfl_xor(sm, off, 16);
        const float inv = __builtin_amdgcn_rcpf(sm);
        #pragma unroll
        for (int cw = 0; cw < 4; ++cw) {
            const int cc = (nl + cw * 16) ^ (row & 7);
            *(uint4*)&Ws[row * 256 + cc * 4] = make_uint4(
                packbf(v[cw * 8 + 0] * inv, v[cw * 8 + 1] * inv),
                packbf(v[cw * 8 + 2] * inv, v[cw * 8 + 3] * inv),
                packbf(v[cw * 8 + 4] * inv, v[cw * 8 + 5] * inv),
                packbf(v[cw * 8 + 6] * inv, v[cw * 8 + 7] * inv));
        }
    }
    __syncthreads();

    f32x4 acc = {0.f, 0.f, 0.f, 0.f};
    {
        const uint16_t* vb = vT + ((size_t)(h * 64 + wv * 16 + nl)) * 512 + g * 8;
        #pragma unroll
        for (int ks = 0; ks < 16; ++ks) {
            const s16x8 a = *(const s16x8*)&Ws[nl * 256 + (((ks * 4 + g) ^ (nl & 7)) << 2)];
            const s16x8 b = *(const s16x8*)&vb[ks * 32];
            acc = __builtin_amdgcn_mfma_f32_16x16x32_bf16(a, b, acc, 0, 0, 0);
        }
    }

    const int n = wv * 16 + nl;
    if (n < 60) {
        int col;
        if (n < 16)      col = h * 16 + n;
        else if (n < 40) col = 128 + h * 24 + (n - 16);
        else             col = 320 + h * 20 + (n - 40);
        #pragma unroll
        for (int rg = 0; rg < 4; ++rg) {
            const size_t o = (size_t)(r0 + g * 4 + rg) * 480 + col;
            float val = ldin(nfu, o, f32) + acc[rg];
            if (f32) ((float*)out)[o] = val;
            else     ((uint16_t*)out)[o] = f2bf(val);
        }
    }
}

// =================================================== standalone kernels (fallback)
__global__ __launch_bounds__(256) void kW(
    const void* __restrict__ mW1, const void* __restrict__ mb1,
    const void* __restrict__ mW2, const void* __restrict__ mb2,
    const void* __restrict__ mW3, const void* __restrict__ mb3,
    const void* __restrict__ Wq0, const void* __restrict__ Wq1, const void* __restrict__ Wq2,
    const void* __restrict__ Wk0, const void* __restrict__ Wk1, const void* __restrict__ Wk2,
    const void* __restrict__ Wv0, const void* __restrict__ Wv1, const void* __restrict__ Wv2,
    float* __restrict__ ws, const void* __restrict__ nfu, int* __restrict__ flagp)
{
    __shared__ int sflag;
    const int t = threadIdx.x;
    if (t < 64) {
        uint32_t x = ((const uint32_t*)nfu)[64 + t];
        int e = (x >> 7) & 0xff;
        int good = (x != 0u) && (e >= 100) && (e <= 140);
        unsigned long long m = __ballot(good);
        if (t == 0) sflag = (__popcll(m) < 32) ? 1 : 0;
    }
    __syncthreads();
    const int f32 = sflag;
    if (blockIdx.x == 0 && t == 0) flagp[0] = f32;
    dPhaseW(mW1, mb1, mW2, mb2, mW3, mb3, Wq0, Wq1, Wq2, Wk0, Wk1, Wk2,
            Wv0, Wv1, Wv2, ws, f32, blockIdx.x * 256 + t, 16384);
}

__global__ __launch_bounds__(256) void kA(
    const void* __restrict__ nfu,
    const float* __restrict__ WtQ, const float* __restrict__ WtK,
    const float* __restrict__ WtV, const float* __restrict__ W1T,
    uint32_t* __restrict__ qG, uint32_t* __restrict__ kG, uint16_t* __restrict__ vT,
    uint32_t* __restrict__ ArecG, uint32_t* __restrict__ AsndG,
    const int* __restrict__ flagp)
{
    __shared__ float nfs[480];
    dPhaseA(nfu, WtQ, WtK, WtV, W1T, qG, kG, vT, ArecG, AsndG,
            flagp[0], blockIdx.x >> 1, blockIdx.x & 1, nfs);
}

__global__ __launch_bounds__(256, 4) void kB(
    const void* __restrict__ eaG, const void* __restrict__ shG,
    const uint32_t* __restrict__ ArecG, const uint32_t* __restrict__ AsndG,
    const uint32_t* __restrict__ qG, const uint32_t* __restrict__ kG,
    const uint32_t* __restrict__ W2B, const uint32_t* __restrict__ W3B,
    const uint32_t* __restrict__ W1B,
    const float* __restrict__ Wf, float* __restrict__ L,
    const int* __restrict__ flagp)
{
    __shared__ __align__(16) uint32_t smem[10240];
    dPhaseB(eaG, shG, ArecG, AsndG, qG, kG, W2B, W3B, W1B, Wf, L,
            flagp[0], blockIdx.x, blockIdx.y, smem);
}

__global__ __launch_bounds__(256) void kAgg(
    const float* __restrict__ L, const uint16_t* __restrict__ vT,
    const void* __restrict__ nfu, void* __restrict__ out,
    const int* __restrict__ flagp)
{
    __shared__ __align__(16) uint32_t Ws[4096];
    dPhaseAgg(L, vT, nfu, out, flagp[0], blockIdx.x, blockIdx.y, Ws);
}

// =================================================== fused cooperative kernel
// Grid-stride phases: correct at ANY grid size (residency decided on host).
__global__ __launch_bounds__(256, 4) void kFused(
    const void* nf, const void* eaG, const void* shG,
    const void* Wq0, const void* Wq1, const void* Wq2,
    const void* Wk0, const void* Wk1, const void* Wk2,
    const void* Wv0, const void* Wv1, const void* Wv2,
    const void* mW1, const void* mb1, const void* mW2, const void* mb2,
    const void* mW3, const void* mb3,
    float* ws, void* out)
{
    __shared__ __align__(16) uint32_t smem[10240];
    const int t = threadIdx.x;
    const int bid = blockIdx.x;
    const int nblk = gridDim.x;

    uint32_t* qG = (uint32_t*)(ws + QG_OFF);
    uint32_t* kG = (uint32_t*)(ws + KG_OFF);
    uint32_t* W2B = (uint32_t*)(ws + W2B_OFF);
    uint32_t* W3B = (uint32_t*)(ws + W3B_OFF);
    uint32_t* W1B = (uint32_t*)(ws + W1B_OFF);
    uint16_t* vT = (uint16_t*)(ws + VT_OFF);
    uint32_t* ArecG = (uint32_t*)(ws + ARE_OFF);
    uint32_t* AsndG = (uint32_t*)(ws + ASN_OFF);
    float* Wf  = ws + WF_OFF;
    float* L   = ws + L_OFF;
    float* WtQ = ws + WTQ_OFF;
    float* WtK = ws + WTK_OFF;
    float* WtV = ws + WTV_OFF;
    float* W1T = ws + W1T_OFF;

    // per-block dtype detection (no global flag dependency)
    if (t < 64) {
        uint32_t x = ((const uint32_t*)nf)[64 + t];
        int e = (x >> 7) & 0xff;
        int good = (x != 0u) && (e >= 100) && (e <= 140);
        unsigned long long m = __ballot(good);
        if (t == 0) smem[0] = (__popcll(m) < 32) ? 1u : 0u;
    }
    __syncthreads();
    const int f32 = (int)smem[0];
    __syncthreads();

    cg::grid_group grid = cg::this_grid();

    // ---- phase W: weight prep spread over the full grid ----
    dPhaseW(mW1, mb1, mW2, mb2, mW3, mb3, Wq0, Wq1, Wq2, Wk0, Wk1, Wk2,
            Wv0, Wv1, Wv2, ws, f32, bid * 256 + t, nblk * 256);
    __threadfence();
    grid.sync();

    // ---- phase A: 2 work items per node, grid-strided ----
    for (int wk = bid; wk < 1024; wk += nblk) {
        dPhaseA(nf, WtQ, WtK, WtV, W1T, qG, kG, vT, ArecG, AsndG,
                f32, wk >> 1, wk & 1, (float*)smem);
        __syncthreads();
    }
    __threadfence();
    grid.sync();

    // ---- phase B: 32x32 edge tiles, grid-strided ----
    for (int wk = bid; wk < 1024; wk += nblk) {
        dPhaseB(eaG, shG, ArecG, AsndG, qG, kG, W2B, W3B, W1B, Wf, L,
                f32, wk & 31, wk >> 5, smem);
        __syncthreads();
    }
    __threadfence();
    grid.sync();

    // ---- phase Agg: 256 work items, grid-strided ----
    for (int wk = bid; wk < 256; wk += nblk) {
        dPhaseAgg(L, vT, nf, out, f32, wk & 31, wk >> 5, smem);
        __syncthreads();
    }
}

extern "C" void kernel_launch(void* const* d_in, const int* in_sizes, int n_in,
                              void* d_out, int out_size, void* d_ws, size_t ws_size,
                              hipStream_t stream)
{
    (void)in_sizes; (void)n_in; (void)out_size; (void)ws_size;
    const void* nf  = d_in[0];
    const void* eaG = d_in[1];
    const void* shG = d_in[2];

    float* ws = (float*)d_ws;
    uint32_t* qG = (uint32_t*)(ws + QG_OFF);
    uint32_t* kG = (uint32_t*)(ws + KG_OFF);
    uint32_t* W2B = (uint32_t*)(ws + W2B_OFF);
    uint32_t* W3B = (uint32_t*)(ws + W3B_OFF);
    uint32_t* W1B = (uint32_t*)(ws + W1B_OFF);
    uint16_t* vT = (uint16_t*)(ws + VT_OFF);
    uint32_t* ArecG = (uint32_t*)(ws + ARE_OFF);
    uint32_t* AsndG = (uint32_t*)(ws + ASN_OFF);
    float* Wf  = ws + WF_OFF;
    int* flag  = (int*)(ws + FLAG_OFF);
    float* L   = ws + L_OFF;
    float* WtQ = ws + WTQ_OFF;
    float* WtK = ws + WTK_OFF;
    float* WtV = ws + WTV_OFF;
    float* W1T = ws + W1T_OFF;

    // ---- cooperative path: residency-checked, one-shot on failure ----
    // state: -1 = unchecked, 0 = disabled, >0 = coop grid size
    static int coopGrid = -1;
    if (coopGrid == -1) {
        coopGrid = 0;
        int dev = 0;
        if (hipGetDevice(&dev) == hipSuccess) {
            int can = 0;
            if (hipDeviceGetAttribute(&can, hipDeviceAttributeCooperativeLaunch, dev)
                    == hipSuccess && can) {
                int maxBlk = 0;
                if (hipOccupancyMaxActiveBlocksPerMultiprocessor(&maxBlk, kFused, 256, 0)
                        == hipSuccess && maxBlk > 0) {
                    int cus = 0;
                    if (hipDeviceGetAttribute(&cus, hipDeviceAttributeMultiprocessorCount,
                                              dev) == hipSuccess && cus > 0) {
                        long g = (long)maxBlk * (long)cus;
                        if (g > 1024) g = 1024;
                        if (g >= 256) coopGrid = (int)g;
                    }
                }
            }
        }
    }
    if (coopGrid > 0) {
        const void* a_nf = nf;  const void* a_ea = eaG; const void* a_sh = shG;
        const void* a_wq0 = d_in[3],  *a_wq1 = d_in[4],  *a_wq2 = d_in[5];
        const void* a_wk0 = d_in[6],  *a_wk1 = d_in[7],  *a_wk2 = d_in[8];
        const void* a_wv0 = d_in[9],  *a_wv1 = d_in[10], *a_wv2 = d_in[11];
        const void* a_m1 = d_in[12], *a_b1 = d_in[13], *a_m2 = d_in[14];
        const void* a_b2 = d_in[15], *a_m3 = d_in[16], *a_b3 = d_in[17];
        float* a_ws = ws; void* a_out = d_out;
        void* args[] = {
            &a_nf, &a_ea, &a_sh,
            &a_wq0, &a_wq1, &a_wq2, &a_wk0, &a_wk1, &a_wk2,
            &a_wv0, &a_wv1, &a_wv2,
            &a_m1, &a_b1, &a_m2, &a_b2, &a_m3, &a_b3,
            &a_ws, &a_out };
        hipError_t err = hipLaunchCooperativeKernel(
            reinterpret_cast<const void*>(&kFused),
            dim3((unsigned)coopGrid), dim3(256), args, 0, stream);
        if (err == hipSuccess) return;
        coopGrid = 0;   // never retry after a failure (protects later captures)
    }

    // ---- fallback: 4-dispatch pipeline (R19 structure, kA at 1024 blocks) ----
    kW<<<64, 256, 0, stream>>>(d_in[12], d_in[13], d_in[14], d_in[15], d_in[16], d_in[17],
                               d_in[3], d_in[4], d_in[5], d_in[6], d_in[7], d_in[8],
                               d_in[9], d_in[10], d_in[11], ws, nf, flag);
    kA<<<1024, 256, 0, stream>>>(nf, WtQ, WtK, WtV, W1T, qG, kG, vT, ArecG, AsndG, flag);
    kB<<<dim3(32, 32), 256, 0, stream>>>(eaG, shG, ArecG, AsndG, qG, kG, W2B, W3B, W1B, Wf, L, flag);
    kAgg<<<dim3(32, 8), 256, 0, stream>>>(L, vT, nf, d_out, flag);
}

// Round 11
// 200.964 us; speedup vs baseline: 1.5110x; 1.5110x over previous
//
#include <hip/hip_runtime.h>
#include <hip/hip_bf16.h>
#include <stdint.h>

// ---------------------------------------------------------------------------
// EquivariantAttention on MI355X.  Dtype-adaptive (bf16 or fp32 inputs).
// R16: single-L-write kB + softmax fused into kAgg; kSM deleted.  kB 70, tot 231.
// R17: pre-converted bf16 q/k tiles + prebuilt W fragment images.  kB 58.6.
// R18: kAgg as per-(r-tile, head) MFMA GEMM.  tot 198.6.
// R19: kB ea@W1a -> MFMA (in-wave shfl A-frags).  kB 48.6, tot 188.8.
// R20/R21: fused cooperative kernel MEASURED REGRESSION (303.7us): VGPR 148,
//   occ 12%, WRITE 242MB — single-kernel register pressure + grid-sync
//   serialization dwarf the ~20us of boundary savings.  Coop abandoned.
// R22: revert to R19-proven 4-dispatch structure +
//   (a) kB phase-0a q/k tiles prefetched into REGISTERS at kernel top (T14
//       async-stage): L2 latency hides under phases 1-2; phase 0a is then
//       pure LDS writes.  VGPR 64->~100 (<128 -> 4 blocks/CU band held;
//       counter-check: if VGPR>128 occupancy halves -> revert).
//   (b) kA split 2 blocks/node (1024 blocks): halves per-block serial
//       weight-read latency.
// ---------------------------------------------------------------------------

#define NNODES 512
#define NDIM   480

// ws layout (4-byte word offsets)
#define QG_OFF    0u         // q bf16 tiles: [rt(32)][h(8)][row(16)][32 u32] = 131072 u32
#define W2B_OFF   131072u    // W2 B-frag bf16 per-lane image: 2048 u32
#define W3B_OFF   133120u    // W3 B-frag bf16 per-lane image: 512 u32
#define W1B_OFF   133632u    // W1a B-frag bf16 per-lane image: 1024 u32
#define KG_OFF    245760u    // k bf16 tiles, same layout as qG
#define VT_OFF    491520u    // v bf16 transposed: [h(8)][j(64)][s(512)] u16 = 512KB
#define ARE_OFF   737280u    // 512*288 u32 (bf16 pairs over o): [n][mi(9)][oc(32)]
#define ASN_OFF   884736u    // 512*288 u32
#define WF_OFF    1032192u   // W1a[32][64]@0, b1@6656, b2@6720, b3@6784
#define FLAG_OFF  1040384u   // flag[0] = 1 if inputs fp32, 0 if bf16
#define L_OFF     1040448u   // L SoA: [h(8)][r(512)][s(512)] f32 (8MB)
#define WTQ_OFF   3137600u   // q weights transposed [o][i] f32 + folds
#define WTK_OFF   3159104u
#define WTV_OFF   3180608u
#define W1T_OFF   3202112u   // mW1 transposed [o(64)][row(480)] f32, cg folded

typedef float f32x4 __attribute__((ext_vector_type(4)));
typedef short s16x8 __attribute__((ext_vector_type(8)));

__device__ __forceinline__ float bf2f(uint16_t u) {
    return __uint_as_float(((uint32_t)u) << 16);
}
__device__ __forceinline__ uint16_t f2bf(float f) {
    union { __hip_bfloat16 h; uint16_t u; } cv;
    cv.h = __float2bfloat16(f);
    return cv.u;
}
__device__ __forceinline__ uint32_t packbf(float lo, float hi) {
    return ((uint32_t)f2bf(hi) << 16) | (uint32_t)f2bf(lo);
}
__device__ __forceinline__ float ldin(const void* p, size_t i, int f32) {
    return f32 ? ((const float*)p)[i] : bf2f(((const uint16_t*)p)[i]);
}
// tanh(x) = 1 - 2/(exp(2x)+1)
__device__ __forceinline__ float ftanh(float x) {
    float e = __builtin_amdgcn_exp2f(x * 2.885390081777927f);
    return 1.0f - 2.0f * __builtin_amdgcn_rcpf(e + 1.0f);
}

// ---------------------------------------------------------------- weights prep
// (kDet fused: every block self-detects dtype from nf; block 0 publishes flag.)
#define NS 16384
__global__ __launch_bounds__(256) void kW(
    const void* __restrict__ mW1, const void* __restrict__ mb1,
    const void* __restrict__ mW2, const void* __restrict__ mb2,
    const void* __restrict__ mW3, const void* __restrict__ mb3,
    const void* __restrict__ Wq0, const void* __restrict__ Wq1, const void* __restrict__ Wq2,
    const void* __restrict__ Wk0, const void* __restrict__ Wk1, const void* __restrict__ Wk2,
    const void* __restrict__ Wv0, const void* __restrict__ Wv1, const void* __restrict__ Wv2,
    float* __restrict__ ws, const void* __restrict__ nfu, int* __restrict__ flagp)
{
    __shared__ int sflag;
    const int t = threadIdx.x;
    if (t < 64) {
        uint32_t x = ((const uint32_t*)nfu)[64 + t];
        int e = (x >> 7) & 0xff;
        int good = (x != 0u) && (e >= 100) && (e <= 140);
        unsigned long long m = __ballot(good);
        if (t == 0) sflag = (__popcll(m) < 32) ? 1 : 0;
    }
    __syncthreads();
    const int f32 = sflag;
    if (blockIdx.x == 0 && t == 0) flagp[0] = f32;

    const int gt = blockIdx.x * 256 + t;
    float* Wf = ws + WF_OFF;

    for (int i = gt; i < 2048; i += NS) Wf[i] = ldin(mW1, i, f32);   // W1a
    for (int i = gt; i < 64; i += NS) Wf[6656 + i] = ldin(mb1, i, f32);
    for (int i = gt; i < 64; i += NS) Wf[6720 + i] = ldin(mb2, i, f32);
    for (int i = gt; i < 8; i += NS)  Wf[6784 + i] = ldin(mb3, i, f32);

    // W2 B-fragment per-lane image: idx = ((nt*2+ks)*64 + lane)*4 + w
    // value = pack(W2[kb][n], W2[kb+1][n]), n = nt*16+(lane&15), kb = ks*32+(lane>>4)*8+2w
    {
        uint32_t* W2B = (uint32_t*)(ws + W2B_OFF);
        for (int i = gt; i < 2048; i += NS) {
            int f = i >> 8, lane = (i >> 2) & 63, w = i & 3;
            int nt = f >> 1, ks = f & 1, nl2 = lane & 15, gg = lane >> 4;
            int n = nt * 16 + nl2, kb = ks * 32 + gg * 8 + 2 * w;
            float lo = ldin(mW2, (size_t)kb * 64 + n, f32);
            float hi = ldin(mW2, (size_t)(kb + 1) * 64 + n, f32);
            W2B[i] = packbf(lo, hi);
        }
        uint32_t* W3B = (uint32_t*)(ws + W3B_OFF);
        for (int i = gt; i < 512; i += NS) {
            int ks = i >> 8, lane = (i >> 2) & 63, w = i & 3;
            int nl2 = lane & 15, gg = lane >> 4;
            int kb = ks * 32 + gg * 8 + 2 * w;
            float lo = (nl2 < 8) ? ldin(mW3, (size_t)kb * 8 + nl2, f32) : 0.f;
            float hi = (nl2 < 8) ? ldin(mW3, (size_t)(kb + 1) * 8 + nl2, f32) : 0.f;
            W3B[i] = packbf(lo, hi);
        }
        // W1a B-fragment: idx = nt*256 + lane*4 + w;
        // value = pack(W1a[k0][n], W1a[k0+1][n]), n = nt*16+(lane&15), k0 = (lane>>4)*8+2w
        uint32_t* W1B = (uint32_t*)(ws + W1B_OFF);
        for (int i = gt; i < 1024; i += NS) {
            int nt = i >> 8, lane = (i >> 2) & 63, w = i & 3;
            int nl2 = lane & 15, gg = lane >> 4;
            int n = nt * 16 + nl2, k0 = gg * 8 + 2 * w;
            W1B[i] = packbf(ldin(mW1, (size_t)k0 * 64 + n, f32),
                            ldin(mW1, (size_t)(k0 + 1) * 64 + n, f32));
        }
    }

    const float e3n0 = 0.08838834764831845f, e3n1 = 0.125f, e3n2 = 0.17677669529663687f;
    const float cg1 = 0.5773502691896258f, cg2 = 0.4472135954999579f;
    const float attn = 0.1889822365046136f;

    const void* Wsrc[9] = {Wq0, Wq1, Wq2, Wk0, Wk1, Wk2, Wv0, Wv1, Wv2};
    float* Wdst[3] = {ws + WTQ_OFF, ws + WTK_OFF, ws + WTV_OFF};
    for (int kind = 0; kind < 3; ++kind) {
        const float f0 = (kind == 0) ? e3n0 * attn : e3n0;
        const float f1 = (kind == 0) ? e3n1 * cg1 * attn : e3n1;
        const float f2 = (kind == 0) ? e3n2 * cg2 * attn : e3n2;
        for (int i = gt; i < 16384; i += NS) {
            int o = i >> 7, ii = i & 127;
            Wdst[kind][i] = ldin(Wsrc[kind * 3], (size_t)ii * 128 + o, f32) * f0;
        }
        for (int i = gt; i < 4096; i += NS) {
            int o = i >> 6, ii = i & 63;
            Wdst[kind][16384 + i] = ldin(Wsrc[kind * 3 + 1], (size_t)ii * 64 + o, f32) * f1;
        }
        for (int i = gt; i < 1024; i += NS) {
            int o = i >> 5, ii = i & 31;
            Wdst[kind][20480 + i] = ldin(Wsrc[kind * 3 + 2], (size_t)ii * 32 + o, f32) * f2;
        }
    }
    float* W1T = ws + W1T_OFF;
    for (int i = gt; i < 30720; i += NS) {
        int o = i / 480, row = i - o * 480;
        float cgv;
        if (row < 160)      cgv = 1.0f;
        else if (row < 224) cgv = cg1;
        else if (row < 256) cgv = cg2;
        else if (row < 384) cgv = 1.0f;
        else if (row < 448) cgv = cg1;
        else                cgv = cg2;
        W1T[i] = ldin(mW1, (size_t)row * 64 + o, f32) * cgv;
    }
}

// ------------------------------------------------- per-node precompute
// 2 blocks per node: half 0 -> q + first half of k + Arec; half 1 -> rest.
__global__ __launch_bounds__(256) void kA(
    const void* __restrict__ nfu,
    const float* __restrict__ WtQ, const float* __restrict__ WtK,
    const float* __restrict__ WtV, const float* __restrict__ W1T,
    uint32_t* __restrict__ qG, uint32_t* __restrict__ kG, uint16_t* __restrict__ vT,
    uint32_t* __restrict__ ArecG, uint32_t* __restrict__ AsndG,
    const int* __restrict__ flagp)
{
    const int f32 = flagp[0];
    const int n = blockIdx.x >> 1, half = blockIdx.x & 1, t = threadIdx.x;
    __shared__ float nfs[480];
    for (int i = t; i < 480; i += 256) nfs[i] = ldin(nfu, (size_t)n * 480 + i, f32);

    // zero-fill tile pad (j = 60..63): half0 -> q,k (64 tasks); half1 -> v (32)
    if (half == 0) {
        if (t < 64) {
            const int kind2 = t >> 5, hh = (t >> 2) & 7, j = 60 + (t & 3);
            const int row = n & 15, rt = n >> 4;
            const int cc = (j >> 3) ^ (n & 7);
            uint16_t* dst = (uint16_t*)(kind2 == 0 ? qG : kG);
            dst[((((size_t)rt * 8 + hh) * 16 + row) * 8 + cc) * 8 + (j & 7)] = 0;
        }
    } else {
        if (t < 32) {
            const int hh = t >> 2, j = 60 + (t & 3);
            vT[((size_t)(hh * 64 + j)) * 512 + n] = 0;
        }
    }
    __syncthreads();

    for (int idx = 720 * half + t; idx < 720 * (half + 1); idx += 256) {
        int kind = idx / 480, rem = idx - kind * 480;
        int o, m, mul, d, off, am, qoff, sub;
        if (rem < 128)      { o = rem;           m = 0;          mul = 128; d = 1; off = 0;   am = 16; qoff = 0;  sub = 0; }
        else if (rem < 320) { int x = rem - 128; o = x / 3; m = x - o * 3; mul = 64;  d = 3; off = 128; am = 8;  qoff = 16; sub = 16384; }
        else                { int x = rem - 320; o = x / 5; m = x - o * 5; mul = 32;  d = 5; off = 320; am = 4;  qoff = 40; sub = 20480; }
        const float* base = (kind == 0) ? WtQ : (kind == 1) ? WtK : WtV;
        const float4* W4 = reinterpret_cast<const float4*>(base + sub + o * mul);
        const float* nf0 = nfs + off + m;
        float ax = 0.f, ay = 0.f, az = 0.f, aw = 0.f;
        const int n4 = mul >> 2;
        for (int i4 = 0; i4 < n4; ++i4) {
            float4 w = W4[i4];
            int ib = 4 * i4 * d;
            ax += nf0[ib]         * w.x;
            ay += nf0[ib + d]     * w.y;
            az += nf0[ib + 2 * d] * w.z;
            aw += nf0[ib + 3 * d] * w.w;
        }
        float acc = (ax + ay) + (az + aw);
        int hh = o / am, a = o - hh * am;
        int j = qoff + a * d + m;
        if (kind == 2) {
            // v bf16 transposed: [h][j][s=n]
            vT[((size_t)(hh * 64 + j)) * 512 + n] = f2bf(acc);
        } else {
            // bf16 pre-swizzled tile write: [rt][hh][row][chunk^(row&7)][j&7]
            const int row = n & 15, rt = n >> 4;
            const int cc = (j >> 3) ^ (n & 7);
            uint16_t* dst = (uint16_t*)(kind == 0 ? qG : kG);
            dst[((((size_t)rt * 8 + hh) * 16 + row) * 8 + cc) * 8 + (j & 7)] = f2bf(acc);
        }
    }

    // A-features: this half does src = half (o = lane of wave 0)
    if (t < 64) {
        const int src = half, o = t;
        float a[9];
        #pragma unroll
        for (int mi = 0; mi < 9; ++mi) {
            const int l = (mi == 0) ? 0 : (mi < 4 ? 1 : 2);
            const int m = (mi == 0) ? 0 : (mi < 4 ? mi - 1 : mi - 4);
            const int mul = (l == 0 ? 128 : l == 1 ? 64 : 32);
            const int d = 2 * l + 1;
            const int off = (l == 0 ? 0 : l == 1 ? 128 : 320);
            const int base = (src == 0) ? (l == 0 ? 32 : l == 1 ? 160 : 224)
                                        : (l == 0 ? 256 : l == 1 ? 384 : 448);
            const float4* W4 = reinterpret_cast<const float4*>(W1T + o * 480 + base);
            const float* nf0 = nfs + off + m;
            float ax = 0.f, ay = 0.f, az = 0.f, aw = 0.f;
            const int n4 = mul >> 2;
            for (int i4 = 0; i4 < n4; ++i4) {
                float4 w = W4[i4];
                int ib = 4 * i4 * d;
                ax += nf0[ib]         * w.x;
                ay += nf0[ib + d]     * w.y;
                az += nf0[ib + 2 * d] * w.z;
                aw += nf0[ib + 3 * d] * w.w;
            }
            a[mi] = (ax + ay) + (az + aw);
        }
        float b[9];
        #pragma unroll
        for (int mi = 0; mi < 9; ++mi) b[mi] = __shfl_xor(a[mi], 1, 64);
        if ((o & 1) == 0) {
            uint32_t* dst = (src ? AsndG : ArecG) + (size_t)n * 288 + (o >> 1);
            #pragma unroll
            for (int mi = 0; mi < 9; ++mi)
                dst[mi * 32] = ((uint32_t)f2bf(b[mi]) << 16) | (uint32_t)f2bf(a[mi]);
        }
    }
}

// ------------------------------------------------- edge MLP + logits (full grid)
// Phase 1a (MFMA): eaPart = ea @ W1a -> bf16 h-tile (A-frags via in-wave shfl)
// Phase 1b (VALU): h = eaPart + b1 + sh.(Arec+Asnd) ; tanh
// Phase 2 (MFMA, per-mm fused): h2 = tanh(b2 + h@W2) ; ew = b3 + h2@W3 -> ewS (LDS)
// Phase 0 (MFMA, LAST): q/k tiles (PREFETCHED to regs at top) -> logits = q.k ;
//                       L = logits + ew (ONE write)
__global__ __launch_bounds__(256, 4) void kB(
    const void* __restrict__ eaG, const void* __restrict__ shG,
    const uint32_t* __restrict__ ArecG, const uint32_t* __restrict__ AsndG,
    const uint32_t* __restrict__ qG, const uint32_t* __restrict__ kG,
    const uint32_t* __restrict__ W2B, const uint32_t* __restrict__ W3B,
    const uint32_t* __restrict__ W1B,
    const float* __restrict__ Wf, float* __restrict__ L,
    const int* __restrict__ flagp)
{
    // words [0,8192)   ea-partial tile / Arec+Asnd / h-tile / q,k tiles (time-shared)
    // words [0,4672)   ArecS        (phase 1b)
    // words [4672,9344) AsndS       (phase 1b)
    // words [8192,10240) ewS: [h(8)][e2(256)^ (h<<2)] f32  (written ph2, read ph0)
    __shared__ __align__(16) uint32_t smem[10240];   // 40960 B = 160KB / 4
    uint32_t* ArecS = smem;
    uint32_t* AsndS = smem + 4672;
    float* ewS = (float*)(smem + 8192);
    const int f32 = flagp[0];
    const int t = threadIdx.x;
    const int s0 = blockIdx.x * 16, r0 = blockIdx.y * 16;
    const int lane = t & 63, wv = t >> 6;
    const int g = lane >> 4, nl = lane & 15;

    const int rl = t >> 4, sl = t & 15;
    const int r = r0 + rl, s = s0 + sl;
    const size_t eidx = (((size_t)r) << 9) + s;

    // ---- T14 prefetch: q/k tiles into registers (consumed in phase 0a) ----
    uint4 qv[4], kv[4];
    {
        const uint4* qg4 = (const uint4*)qG + (size_t)blockIdx.y * 1024;
        const uint4* kg4 = (const uint4*)kG + (size_t)blockIdx.x * 1024;
        #pragma unroll
        for (int m = 0; m < 4; ++m) {
            qv[m] = qg4[t + 256 * m];
            kv[m] = kg4[t + 256 * m];
        }
    }

    // ---- per-edge ea / sh loads early (registers; independent of LDS) ----
    uint32_t eaR[16];
    if (f32) {
        const float4* ep = reinterpret_cast<const float4*>((const float*)eaG + eidx * 32);
        #pragma unroll
        for (int i = 0; i < 8; ++i) {
            float4 v = ep[i];
            eaR[2 * i]     = ((uint32_t)f2bf(v.y) << 16) | (uint32_t)f2bf(v.x);
            eaR[2 * i + 1] = ((uint32_t)f2bf(v.w) << 16) | (uint32_t)f2bf(v.z);
        }
    } else {
        const uint4* ep = reinterpret_cast<const uint4*>((const uint32_t*)eaG + eidx * 16);
        #pragma unroll
        for (int i = 0; i < 4; ++i) {
            uint4 v = ep[i];
            eaR[4 * i] = v.x; eaR[4 * i + 1] = v.y; eaR[4 * i + 2] = v.z; eaR[4 * i + 3] = v.w;
        }
    }

    float sh0, sh1, sh2, sh3, sh4, sh5, sh6, sh7, sh8;
    {
        const size_t sb = eidx * 9;
        if (f32) {
            const float* shp = (const float*)shG + sb;
            sh0 = shp[0]; sh1 = shp[1]; sh2 = shp[2]; sh3 = shp[3]; sh4 = shp[4];
            sh5 = shp[5]; sh6 = shp[6]; sh7 = shp[7]; sh8 = shp[8];
        } else {
            const uint16_t* shp = (const uint16_t*)shG + sb;
            sh0 = bf2f(shp[0]); sh1 = bf2f(shp[1]); sh2 = bf2f(shp[2]);
            sh3 = bf2f(shp[3]); sh4 = bf2f(shp[4]); sh5 = bf2f(shp[5]);
            sh6 = bf2f(shp[6]); sh7 = bf2f(shp[7]); sh8 = bf2f(shp[8]);
        }
    }

    // ---- phase 1a: eaPart = ea @ W1a via MFMA (K=32, one MFMA per n-tile) ----
    // A-frag rows (edges mt*16+nl) are owned by lanes mm*16+nl of THIS wave ->
    // gather via compile-time-indexed shuffles.  C written bf16 into the h-tile
    // region (rows [wv*64,wv*64+64) only -> intra-wave, no barrier needed before
    // this wave's own-row read below).
    {
        s16x8 w1f[4];
        #pragma unroll
        for (int nt = 0; nt < 4; ++nt) w1f[nt] = ((const s16x8*)W1B)[nt * 64 + lane];
        uint16_t* sm16 = (uint16_t*)smem;
        #pragma unroll
        for (int mm = 0; mm < 4; ++mm) {
            const int srcl = mm * 16 + nl;
            uint32_t af0 = 0, af1 = 0, af2 = 0, af3 = 0;
            #pragma unroll
            for (int c = 0; c < 16; ++c) {
                const uint32_t tmp = (uint32_t)__shfl((int)eaR[c], srcl, 64);
                if ((c >> 2) == g) {
                    if ((c & 3) == 0)      af0 = tmp;
                    else if ((c & 3) == 1) af1 = tmp;
                    else if ((c & 3) == 2) af2 = tmp;
                    else                   af3 = tmp;
                }
            }
            union { uint32_t u[4]; s16x8 v; } afc;
            afc.u[0] = af0; afc.u[1] = af1; afc.u[2] = af2; afc.u[3] = af3;
            const s16x8 afrag = afc.v;
            const int mt = wv * 4 + mm;
            #pragma unroll
            for (int nt = 0; nt < 4; ++nt) {
                f32x4 a = {0.f, 0.f, 0.f, 0.f};
                a = __builtin_amdgcn_mfma_f32_16x16x32_bf16(afrag, w1f[nt], a, 0, 0, 0);
                #pragma unroll
                for (int rg = 0; rg < 4; ++rg) {
                    const int e = mt * 16 + g * 4 + rg;
                    const int o = nt * 16 + nl;
                    sm16[e * 64 + (((o >> 3) ^ (e & 7)) << 3) + (o & 7)] = f2bf(a[rg]);
                }
            }
        }
    }

    // ---- h init: own row's ea-partial (intra-wave LDS dep) + b1 ----
    float h[64];
    #pragma unroll
    for (int c = 0; c < 8; ++c) {
        const int cc = c ^ (t & 7);
        const uint4 p = *(const uint4*)&smem[t * 32 + cc * 4];
        h[c * 8 + 0] = __uint_as_float(p.x << 16);
        h[c * 8 + 1] = __uint_as_float(p.x & 0xffff0000u);
        h[c * 8 + 2] = __uint_as_float(p.y << 16);
        h[c * 8 + 3] = __uint_as_float(p.y & 0xffff0000u);
        h[c * 8 + 4] = __uint_as_float(p.z << 16);
        h[c * 8 + 5] = __uint_as_float(p.z & 0xffff0000u);
        h[c * 8 + 6] = __uint_as_float(p.w << 16);
        h[c * 8 + 7] = __uint_as_float(p.w & 0xffff0000u);
    }
    #pragma unroll
    for (int o = 0; o < 64; ++o) h[o] += Wf[6656 + o];   // b1

    __syncthreads();   // all waves done reading ea-partial before restage

    // ---- stage Arec/Asnd (overwrites ea-partial region) ----
    for (int i = t; i < 16 * 288; i += 256) {
        int row = i / 288, c = i - row * 288;
        ArecS[row * 292 + c] = ArecG[(size_t)(r0 + row) * 288 + c];
        AsndS[row * 292 + c] = AsndG[(size_t)(s0 + row) * 288 + c];
    }
    __syncthreads();

    // ---- phase 1b: sh.(Arec+Asnd) ----
    {
        const int rb = rl * 292, sb = sl * 292;
        #pragma unroll 1
        for (int mi = 0; mi < 9; ++mi) {
            float shv = sh0;
            shv = (mi == 1) ? sh1 : shv;  shv = (mi == 2) ? sh2 : shv;
            shv = (mi == 3) ? sh3 : shv;  shv = (mi == 4) ? sh4 : shv;
            shv = (mi == 5) ? sh5 : shv;  shv = (mi == 6) ? sh6 : shv;
            shv = (mi == 7) ? sh7 : shv;  shv = (mi == 8) ? sh8 : shv;
            const int ro = rb + mi * 32, so = sb + mi * 32;
            #pragma unroll
            for (int oc = 0; oc < 32; ++oc) {
                uint32_t pa = ArecS[ro + oc];
                uint32_t pb = AsndS[so + oc];
                float a0 = __uint_as_float(pa << 16);
                float b0 = __uint_as_float(pb << 16);
                float a1 = __uint_as_float(pa & 0xffff0000u);
                float b1 = __uint_as_float(pb & 0xffff0000u);
                h[2 * oc]     += shv * (a0 + b0);
                h[2 * oc + 1] += shv * (a1 + b1);
            }
        }
    }

    #pragma unroll
    for (int o = 0; o < 64; ++o) h[o] = ftanh(h[o]);

    // ---- pack h -> bf16, write swizzled LDS tile (row e = t, stride 32 u32;
    //      16B chunk c stored at c ^ (row&7)) ----
    __syncthreads();   // all ArecS/AsndS reads complete before overwrite
    #pragma unroll
    for (int c = 0; c < 8; ++c) {
        const int cc = c ^ (t & 7);
        *(uint4*)&smem[t * 32 + cc * 4] =
            make_uint4(packbf(h[c * 8 + 0], h[c * 8 + 1]),
                       packbf(h[c * 8 + 2], h[c * 8 + 3]),
                       packbf(h[c * 8 + 4], h[c * 8 + 5]),
                       packbf(h[c * 8 + 6], h[c * 8 + 7]));
    }
    // Pin: nothing below (W-fragment loads) may be hoisted above this point —
    // keeping phase-1 peak pressure low is the point (R14).
    __builtin_amdgcn_sched_barrier(0);

    // ---- W2/W3 B-fragments: direct 16B loads of prebuilt per-lane images ----
    s16x8 w2f[4][2];
    #pragma unroll
    for (int nt = 0; nt < 4; ++nt) {
        #pragma unroll
        for (int ks = 0; ks < 2; ++ks)
            w2f[nt][ks] = ((const s16x8*)W2B)[(nt * 2 + ks) * 64 + lane];
    }
    s16x8 w3f[2];
    w3f[0] = ((const s16x8*)W3B)[lane];
    w3f[1] = ((const s16x8*)W3B)[64 + lane];
    float b2v[4];
    #pragma unroll
    for (int nt = 0; nt < 4; ++nt) b2v[nt] = Wf[6720 + nt * 16 + nl];
    const float b3v = (nl < 8) ? Wf[6784 + nl] : 0.f;

    // From here on every h-tile LDS row this wave touches is in
    // [wv*64, wv*64+64): written by this wave's own threads -> no barriers
    // needed inside phase 2 (per-wave LDS ordering + compiler lgkmcnt).

    // ---- phase 2 fused per-mm: layer2 -> tanh -> h2 pack -> layer3 -> ewS ----
    uint16_t* sm16 = (uint16_t*)smem;
    #pragma unroll 1
    for (int mm = 0; mm < 4; ++mm) {
        const int mt = wv * 4 + mm;
        const int row = mt * 16 + nl;
        const int sw0 = ((g    ) ^ (row & 7)) * 4;
        const int sw1 = ((4 + g) ^ (row & 7)) * 4;
        // layer 2: A-frag row = mt*16 + (l&15), k = ks*32 + (l>>4)*8 + j
        const s16x8 a0 = *(const s16x8*)&smem[row * 32 + sw0];
        const s16x8 a1 = *(const s16x8*)&smem[row * 32 + sw1];
        f32x4 acc[4];
        #pragma unroll
        for (int nt = 0; nt < 4; ++nt) {
            f32x4 a = {b2v[nt], b2v[nt], b2v[nt], b2v[nt]};
            a = __builtin_amdgcn_mfma_f32_16x16x32_bf16(a0, w2f[nt][0], a, 0, 0, 0);
            a = __builtin_amdgcn_mfma_f32_16x16x32_bf16(a1, w2f[nt][1], a, 0, 0, 0);
            acc[nt] = a;
        }
        // tanh + h2 write (bf16, same swizzle; C layout: col=l&15, row=g*4+reg)
        const int e2base = mt * 16 + g * 4;
        #pragma unroll
        for (int nt = 0; nt < 4; ++nt) {
            const int n = nt * 16 + nl;
            #pragma unroll
            for (int rg = 0; rg < 4; ++rg) {
                const int e2 = e2base + rg;
                const int cc = (n >> 3) ^ (e2 & 7);
                sm16[e2 * 64 + cc * 8 + (n & 7)] = f2bf(ftanh(acc[nt][rg]));
            }
        }
        // layer 3: re-read same rows (now h2) — in-wave LDS ordering guarantees
        // the writes above are observed.
        const s16x8 c0 = *(const s16x8*)&smem[row * 32 + sw0];
        const s16x8 c1 = *(const s16x8*)&smem[row * 32 + sw1];
        f32x4 a3 = {b3v, b3v, b3v, b3v};
        a3 = __builtin_amdgcn_mfma_f32_16x16x32_bf16(c0, w3f[0], a3, 0, 0, 0);
        a3 = __builtin_amdgcn_mfma_f32_16x16x32_bf16(c1, w3f[1], a3, 0, 0, 0);
        if (nl < 8) {
            // ew -> LDS scratch (read back in phase 0b); XOR swizzle -> 4-way
            #pragma unroll
            for (int rg = 0; rg < 4; ++rg) {
                const int e2 = mt * 16 + g * 4 + rg;
                ewS[nl * 256 + (e2 ^ (nl << 2))] = a3[rg];
            }
        }
    }

    __syncthreads();   // phase-2 h-tile reads + ewS writes complete

    // ---- phase 0a: write prefetched q/k bf16 tiles -> LDS (pure ds_write) ----
    {
        uint4* sm4 = (uint4*)smem;
        #pragma unroll
        for (int m = 0; m < 4; ++m) {
            sm4[t + 256 * m] = qv[m];
            sm4[1024 + t + 256 * m] = kv[m];
        }
    }
    __syncthreads();

    // ---- phase 0b: logits = q.k via MFMA; L = logits + ew (single write) ----
    {
        const int sw0 = ((g    ) ^ (nl & 7)) << 2;
        const int sw1 = ((4 + g) ^ (nl & 7)) << 2;
        #pragma unroll
        for (int hh2 = 0; hh2 < 2; ++hh2) {
            const int h2 = wv * 2 + hh2;
            const uint32_t* qb = smem + h2 * 512;
            const uint32_t* kb = smem + 4096 + h2 * 512;
            const s16x8 qa0 = *(const s16x8*)&qb[nl * 32 + sw0];
            const s16x8 qa1 = *(const s16x8*)&qb[nl * 32 + sw1];
            const s16x8 ka0 = *(const s16x8*)&kb[nl * 32 + sw0];
            const s16x8 ka1 = *(const s16x8*)&kb[nl * 32 + sw1];
            f32x4 a = {0.f, 0.f, 0.f, 0.f};
            a = __builtin_amdgcn_mfma_f32_16x16x32_bf16(qa0, ka0, a, 0, 0, 0);
            a = __builtin_amdgcn_mfma_f32_16x16x32_bf16(qa1, ka1, a, 0, 0, 0);
            float* Lp = L + (((size_t)h2) << 18) + (((size_t)(r0 + g * 4)) << 9) + s0 + nl;
            #pragma unroll
            for (int rg = 0; rg < 4; ++rg) {
                const int e2 = (g * 4 + rg) * 16 + nl;
                Lp[(size_t)rg << 9] = a[rg] + ewS[h2 * 256 + (e2 ^ (h2 << 2))];
            }
        }
    }
}

// ------------------------------------------------- softmax + aggregation (MFMA)
// Block = (16-row r-tile, head h).  out_h[16 x 60] = softmax(L_h)[16x512] @ V_h.
// Softmax: 16-lane groups per row; bf16 A-tile in 16KB swizzled LDS.
// GEMM: wave = one 16-col n-tile; B-frags are 16B contiguous vT global loads.
__global__ __launch_bounds__(256) void kAgg(
    const float* __restrict__ L, const uint16_t* __restrict__ vT,
    const void* __restrict__ nfu, void* __restrict__ out,
    const int* __restrict__ flagp)
{
    __shared__ __align__(16) uint32_t Ws[4096];   // [row(16)][chunk(64)^swz][4 u32]
    const int f32 = flagp[0];
    const int t = threadIdx.x;
    const int lane = t & 63, wv = t >> 6;
    const int g = lane >> 4, nl = lane & 15;
    const int r0 = blockIdx.x * 16;
    const int h  = blockIdx.y;

    // ---- softmax: row = wv*4+g, 16 lanes/row; lane owns 4 blocks of 8 cols ----
    {
        const int row = wv * 4 + g;
        const float* Lg = L + (((size_t)h) << 18) + (((size_t)(r0 + row)) << 9);
        float v[32];
        #pragma unroll
        for (int cw = 0; cw < 4; ++cw) {
            const float4* p = reinterpret_cast<const float4*>(Lg + nl * 8 + cw * 128);
            float4 x = p[0], y = p[1];
            v[cw * 8 + 0] = x.x; v[cw * 8 + 1] = x.y; v[cw * 8 + 2] = x.z; v[cw * 8 + 3] = x.w;
            v[cw * 8 + 4] = y.x; v[cw * 8 + 5] = y.y; v[cw * 8 + 6] = y.z; v[cw * 8 + 7] = y.w;
        }
        float mx = -3.402823466e38f;
        #pragma unroll
        for (int i = 0; i < 32; ++i) mx = fmaxf(mx, v[i]);
        #pragma unroll
        for (int off = 8; off >= 1; off >>= 1) mx = fmaxf(mx, __shfl_xor(mx, off, 16));
        const float C = 1.4426950408889634f;
        float sm = 0.f;
        #pragma unroll
        for (int i = 0; i < 32; ++i) {
            v[i] = __builtin_amdgcn_exp2f((v[i] - mx) * C);
            sm += v[i];
        }
        #pragma unroll
        for (int off = 8; off >= 1; off >>= 1) sm += __shfl_xor(sm, off, 16);
        const float inv = __builtin_amdgcn_rcpf(sm);
        #pragma unroll
        for (int cw = 0; cw < 4; ++cw) {
            const int cc = (nl + cw * 16) ^ (row & 7);
            *(uint4*)&Ws[row * 256 + cc * 4] = make_uint4(
                packbf(v[cw * 8 + 0] * inv, v[cw * 8 + 1] * inv),
                packbf(v[cw * 8 + 2] * inv, v[cw * 8 + 3] * inv),
                packbf(v[cw * 8 + 4] * inv, v[cw * 8 + 5] * inv),
                packbf(v[cw * 8 + 6] * inv, v[cw * 8 + 7] * inv));
        }
    }
    __syncthreads();

    // ---- GEMM: A = Ws (row=nl, k=ks*32+g*8+j), B = vT[h][n][k] contiguous ----
    f32x4 acc = {0.f, 0.f, 0.f, 0.f};
    {
        const uint16_t* vb = vT + ((size_t)(h * 64 + wv * 16 + nl)) * 512 + g * 8;
        #pragma unroll
        for (int ks = 0; ks < 16; ++ks) {
            const s16x8 a = *(const s16x8*)&Ws[nl * 256 + (((ks * 4 + g) ^ (nl & 7)) << 2)];
            const s16x8 b = *(const s16x8*)&vb[ks * 32];
            acc = __builtin_amdgcn_mfma_f32_16x16x32_bf16(a, b, acc, 0, 0, 0);
        }
    }

    // ---- epilogue: local j -> global column (3 contiguous spans per head) ----
    const int n = wv * 16 + nl;
    if (n < 60) {
        int col;
        if (n < 16)      col = h * 16 + n;
        else if (n < 40) col = 128 + h * 24 + (n - 16);
        else             col = 320 + h * 20 + (n - 40);
        #pragma unroll
        for (int rg = 0; rg < 4; ++rg) {
            const size_t o = (size_t)(r0 + g * 4 + rg) * 480 + col;
            float val = ldin(nfu, o, f32) + acc[rg];
            if (f32) ((float*)out)[o] = val;
            else     ((uint16_t*)out)[o] = f2bf(val);
        }
    }
}

extern "C" void kernel_launch(void* const* d_in, const int* in_sizes, int n_in,
                              void* d_out, int out_size, void* d_ws, size_t ws_size,
                              hipStream_t stream)
{
    (void)in_sizes; (void)n_in; (void)out_size; (void)ws_size;
    const void* nf  = d_in[0];
    const void* eaG = d_in[1];
    const void* shG = d_in[2];

    float* ws = (float*)d_ws;
    uint32_t* qG = (uint32_t*)(ws + QG_OFF);
    uint32_t* kG = (uint32_t*)(ws + KG_OFF);
    uint32_t* W2B = (uint32_t*)(ws + W2B_OFF);
    uint32_t* W3B = (uint32_t*)(ws + W3B_OFF);
    uint32_t* W1B = (uint32_t*)(ws + W1B_OFF);
    uint16_t* vT = (uint16_t*)(ws + VT_OFF);
    uint32_t* ArecG = (uint32_t*)(ws + ARE_OFF);
    uint32_t* AsndG = (uint32_t*)(ws + ASN_OFF);
    float* Wf  = ws + WF_OFF;
    int* flag  = (int*)(ws + FLAG_OFF);
    float* L   = ws + L_OFF;
    float* WtQ = ws + WTQ_OFF;
    float* WtK = ws + WTK_OFF;
    float* WtV = ws + WTV_OFF;
    float* W1T = ws + W1T_OFF;

    kW<<<64, 256, 0, stream>>>(d_in[12], d_in[13], d_in[14], d_in[15], d_in[16], d_in[17],
                               d_in[3], d_in[4], d_in[5], d_in[6], d_in[7], d_in[8],
                               d_in[9], d_in[10], d_in[11], ws, nf, flag);
    kA<<<1024, 256, 0, stream>>>(nf, WtQ, WtK, WtV, W1T, qG, kG, vT, ArecG, AsndG, flag);
    kB<<<dim3(32, 32), 256, 0, stream>>>(eaG, shG, ArecG, AsndG, qG, kG, W2B, W3B, W1B, Wf, L, flag);
    kAgg<<<dim3(32, 8), 256, 0, stream>>>(L, vT, nf, d_out, flag);
}